// Round 9
// baseline (244.378 us; speedup 1.0000x reference)
//
#include <hip/hip_runtime.h>
#include <hip/hip_bf16.h>

#define NN 50000
#define NE 800000
#define DD 96
#define DOUT 64
#define DJ 288          // 3*DD
#define DMAX 64         // fixed CSR stride; max in-degree (Poisson(16)) << 64
#define NXCD 8
#define NPX 6250        // nodes per XCD partition
#define ECH 6400        // edges per chunk (125 chunks * 6400 = NE)

typedef unsigned short u16;
typedef unsigned int u32;
typedef short bf8_t __attribute__((ext_vector_type(8)));   // 8 bf16 in 4 VGPRs
typedef float f4_t __attribute__((ext_vector_type(4)));

// ---------------- bf16 helpers ----------------
__device__ __forceinline__ float bf_lo(u32 u) { return __uint_as_float(u << 16); }
__device__ __forceinline__ float bf_hi(u32 u) { return __uint_as_float(u & 0xffff0000u); }
__device__ __forceinline__ u16 f2bf_rne(float f) {
    u32 u = __float_as_uint(f);
    u32 r = (u + 0x7fffu + ((u >> 16) & 1u)) >> 16;
    return (u16)r;
}

// ---------------- XCD-partitioned degree + slot scatter ----------------
// Edge streams read NON-TEMPORALLY so the XCD-private slot/cursor lines stay
// resident in the per-XCD L2 until their single final writeback (R8 showed a
// 4.5x writeback amplification: 58 MB written for 12.8 MB of slots).
__global__ __launch_bounds__(256)
void pass1_kernel(const int* __restrict__ src, const int* __restrict__ dst,
                  const float* __restrict__ ew, int* __restrict__ deg_out,
                  int* __restrict__ cursor, u32* __restrict__ slots) {
    int xcd = blockIdx.x & 7;
    int chunk = blockIdx.x >> 3;
    int lo = xcd * NPX, hi = lo + NPX;
    int e0 = chunk * ECH;
    for (int e = e0 + threadIdx.x; e < e0 + ECH; e += 256) {
        int s = __builtin_nontemporal_load(src + e);
        int d = __builtin_nontemporal_load(dst + e);
        if (s >= lo && s < hi) atomicAdd(&deg_out[s], 1);
        if (d >= lo && d < hi) {
            float w = __builtin_nontemporal_load(ew + e);
            int r = atomicAdd(&cursor[d], 1);
            if (r < DMAX)
                slots[d * DMAX + r] = (u32)s | ((u32)f2bf_rne(w) << 16);
        }
    }
}

// ---------------- norms: out_norm (in place over deg_out), in_norm ----------------
__global__ void norm_kernel(int* __restrict__ deg_out_i, const int* __restrict__ cursor,
                            float* __restrict__ in_norm) {
    int i = blockIdx.x * blockDim.x + threadIdx.x;
    if (i < NN) {
        float a = rsqrtf(fmaxf((float)deg_out_i[i], 1.0f));
        float b = rsqrtf(fmaxf((float)cursor[i], 1.0f));
        ((float*)deg_out_i)[i] = a;
        in_norm[i] = b;
    }
}

// ---------------- fold out_norm[src] into slot coeff (in place, uint4 granular) ----------------
__global__ __launch_bounds__(256)
void fixup_kernel(u32* __restrict__ slots, const int* __restrict__ cursor,
                  const float* __restrict__ out_norm) {
    int idx4 = blockIdx.x * 256 + threadIdx.x;     // one uint4 (4 slots) per thread
    if (idx4 >= NN * (DMAX / 4)) return;
    int i = idx4 >> 4;
    int k = (idx4 & 15) * 4;
    int deg = min(cursor[i], DMAX);
    if (k >= deg) return;
    uint4 sl = *reinterpret_cast<const uint4*>(slots + i * DMAX + k);
    sl.x = (sl.x & 0xffffu) | ((u32)f2bf_rne(bf_hi(sl.x) * out_norm[sl.x & 0xffffu]) << 16);
    sl.y = (sl.y & 0xffffu) | ((u32)f2bf_rne(bf_hi(sl.y) * out_norm[sl.y & 0xffffu]) << 16);
    sl.z = (sl.z & 0xffffu) | ((u32)f2bf_rne(bf_hi(sl.z) * out_norm[sl.z & 0xffffu]) << 16);
    sl.w = (sl.w & 0xffffu) | ((u32)f2bf_rne(bf_hi(sl.w) * out_norm[sl.w & 0xffffu]) << 16);
    *reinterpret_cast<uint4*>(slots + i * DMAX + k) = sl;
}

// ---------------- cast x (f32 [NN][96]) -> xb (bf16, split layout [3][NN][32]) ----------------
__global__ void cast_kernel(const float* __restrict__ x, u16* __restrict__ xb) {
    int idx = blockIdx.x * 256 + threadIdx.x;
    if (idx < NN * 24) {
        int i = idx / 24;
        int ff = (idx % 24) * 4;
        float4 v = *reinterpret_cast<const float4*>(x + (size_t)i * DD + ff);
        uint2 pk;
        pk.x = (u32)f2bf_rne(v.x) | ((u32)f2bf_rne(v.y) << 16);
        pk.y = (u32)f2bf_rne(v.z) | ((u32)f2bf_rne(v.w) << 16);
        *reinterpret_cast<uint2*>(xb + ((size_t)(ff >> 5) * NN + i) * 32 + (ff & 31)) = pk;
    }
}

// ---------------- cast+transpose weights: W0,W1,W2 -> Wbt[3][96][96]; Wo -> Wot[64][288] ----------------
__global__ void castw_kernel(const float* __restrict__ W0, const float* __restrict__ W1,
                             const float* __restrict__ W2, const float* __restrict__ Wo,
                             u16* __restrict__ Wbt, u16* __restrict__ Wot) {
    int idx = blockIdx.x * 256 + threadIdx.x;
    if (idx < 3 * DD * DD) {
        int L = idx / (DD * DD), rem = idx % (DD * DD);
        int c = rem / DD, k = rem % DD;
        const float* W = (L == 0) ? W0 : (L == 1) ? W1 : W2;
        Wbt[idx] = f2bf_rne(W[k * DD + c]);
    } else if (idx < 3 * DD * DD + DOUT * DJ) {
        int j = idx - 3 * DD * DD;
        int c = j / DJ, k = j % DJ;
        Wot[j] = f2bf_rne(Wo[k * DOUT + c]);
    }
}

// ---------------- slot-CSR aggregation, split-feature, 16-deep MLP ----------------
__device__ __forceinline__ void accum8(float4& A, float4& B, const uint4& q, float w) {
    A.x = fmaf(bf_lo(q.x), w, A.x);
    A.y = fmaf(bf_hi(q.x), w, A.y);
    A.z = fmaf(bf_lo(q.y), w, A.z);
    A.w = fmaf(bf_hi(q.y), w, A.w);
    B.x = fmaf(bf_lo(q.z), w, B.x);
    B.y = fmaf(bf_hi(q.z), w, B.y);
    B.z = fmaf(bf_lo(q.w), w, B.z);
    B.w = fmaf(bf_hi(q.w), w, B.w);
}

__global__ __launch_bounds__(256)
void agg_kernel(const u16* __restrict__ h, const u32* __restrict__ slots,
                const int* __restrict__ cursor, const float* __restrict__ in_norm,
                u16* __restrict__ aggb) {
    int tid = blockIdx.x * 256 + threadIdx.x;
    int i = tid >> 2;
    if (i >= NN) return;
    int f0 = (tid & 3) * 8;
    int deg = min(cursor[i], DMAX);
    int base = i * DMAX;
    float cn = in_norm[i];

#pragma unroll 1
    for (int sp = 0; sp < 3; ++sp) {
        const u16* hs = h + (size_t)sp * NN * 32 + f0;
        float4 A0 = {0.f,0.f,0.f,0.f}, B0 = A0, A1 = A0, B1 = A0,
               A2 = A0, B2 = A0, A3 = A0, B3 = A0;
        int k = 0;
        // 16-deep: preload 4 slot quads, issue 16 independent gathers
        for (; k + 16 <= deg; k += 16) {
            uint4 sl[4];
#pragma unroll
            for (int m = 0; m < 4; ++m)
                sl[m] = *reinterpret_cast<const uint4*>(slots + base + k + m * 4);
            uint4 q[16];
#pragma unroll
            for (int m = 0; m < 4; ++m) {
                q[m * 4 + 0] = *reinterpret_cast<const uint4*>(hs + (sl[m].x & 0xffffu) * 32);
                q[m * 4 + 1] = *reinterpret_cast<const uint4*>(hs + (sl[m].y & 0xffffu) * 32);
                q[m * 4 + 2] = *reinterpret_cast<const uint4*>(hs + (sl[m].z & 0xffffu) * 32);
                q[m * 4 + 3] = *reinterpret_cast<const uint4*>(hs + (sl[m].w & 0xffffu) * 32);
            }
#pragma unroll
            for (int m = 0; m < 4; ++m) {
                accum8(A0, B0, q[m * 4 + 0], bf_hi(sl[m].x));
                accum8(A1, B1, q[m * 4 + 1], bf_hi(sl[m].y));
                accum8(A2, B2, q[m * 4 + 2], bf_hi(sl[m].z));
                accum8(A3, B3, q[m * 4 + 3], bf_hi(sl[m].w));
            }
        }
        for (; k + 4 <= deg; k += 4) {
            uint4 sl = *reinterpret_cast<const uint4*>(slots + base + k);
            uint4 q0 = *reinterpret_cast<const uint4*>(hs + (sl.x & 0xffffu) * 32);
            uint4 q1 = *reinterpret_cast<const uint4*>(hs + (sl.y & 0xffffu) * 32);
            uint4 q2 = *reinterpret_cast<const uint4*>(hs + (sl.z & 0xffffu) * 32);
            uint4 q3 = *reinterpret_cast<const uint4*>(hs + (sl.w & 0xffffu) * 32);
            accum8(A0, B0, q0, bf_hi(sl.x));
            accum8(A1, B1, q1, bf_hi(sl.y));
            accum8(A2, B2, q2, bf_hi(sl.z));
            accum8(A3, B3, q3, bf_hi(sl.w));
        }
        for (; k < deg; ++k) {
            u32 sv = slots[base + k];
            uint4 q = *reinterpret_cast<const uint4*>(hs + (sv & 0xffffu) * 32);
            accum8(A0, B0, q, bf_hi(sv));
        }
        float r0 = ((A0.x + A1.x) + (A2.x + A3.x)) * cn;
        float r1 = ((A0.y + A1.y) + (A2.y + A3.y)) * cn;
        float r2 = ((A0.z + A1.z) + (A2.z + A3.z)) * cn;
        float r3 = ((A0.w + A1.w) + (A2.w + A3.w)) * cn;
        float r4 = ((B0.x + B1.x) + (B2.x + B3.x)) * cn;
        float r5 = ((B0.y + B1.y) + (B2.y + B3.y)) * cn;
        float r6 = ((B0.z + B1.z) + (B2.z + B3.z)) * cn;
        float r7 = ((B0.w + B1.w) + (B2.w + B3.w)) * cn;
        uint4 pk;
        pk.x = (u32)f2bf_rne(r0) | ((u32)f2bf_rne(r1) << 16);
        pk.y = (u32)f2bf_rne(r2) | ((u32)f2bf_rne(r3) << 16);
        pk.z = (u32)f2bf_rne(r4) | ((u32)f2bf_rne(r5) << 16);
        pk.w = (u32)f2bf_rne(r6) | ((u32)f2bf_rne(r7) << 16);
        *reinterpret_cast<uint4*>(aggb + ((size_t)sp * NN + i) * 32 + f0) = pk;
    }
}

// ---------------- MFMA GEMM [NN x 96] @ [96 x 96] + bias + LN (+ReLU) -> bf16 split ----------------
template <int RELU>
__global__ __launch_bounds__(384)
void gemm_mfma_kernel(const u16* __restrict__ aggb, const u16* __restrict__ Wbt,
                      const float* __restrict__ b, const float* __restrict__ g,
                      const float* __restrict__ be, u16* __restrict__ hout) {
    __shared__ float vb[16][97];
    int t = threadIdx.x;
    int w = t >> 6, l = t & 63;
    int col = w * 16 + (l & 15);
    int kb = (l >> 4) * 8;

    bf8_t bfrag[3];
#pragma unroll
    for (int s = 0; s < 3; ++s)
        bfrag[s] = *reinterpret_cast<const bf8_t*>(Wbt + col * DD + s * 32 + kb);

    int rbase = blockIdx.x * 16;
    size_t row = rbase + (l & 15);
    f4_t acc = {0.f, 0.f, 0.f, 0.f};
#pragma unroll
    for (int s = 0; s < 3; ++s) {
        bf8_t a = *reinterpret_cast<const bf8_t*>(aggb + ((size_t)s * NN + row) * 32 + kb);
        acc = __builtin_amdgcn_mfma_f32_16x16x32_bf16(a, bfrag[s], acc, 0, 0, 0);
    }
    float bcol = b[col];
#pragma unroll
    for (int r = 0; r < 4; ++r)
        vb[(l >> 4) * 4 + r][col] = acc[r] + bcol;
    __syncthreads();

    if (t < 256) {
        int rr = t >> 4, q = t & 15;
        float v[6];
#pragma unroll
        for (int c = 0; c < 6; ++c) v[c] = vb[rr][q + 16 * c];
        float s1 = ((v[0] + v[1]) + (v[2] + v[3])) + (v[4] + v[5]);
#pragma unroll
        for (int d = 8; d >= 1; d >>= 1) s1 += __shfl_xor(s1, d, 16);
        float mu = s1 * (1.0f / 96.0f);
        float s2 = 0.f;
#pragma unroll
        for (int c = 0; c < 6; ++c) { v[c] -= mu; s2 += v[c] * v[c]; }
#pragma unroll
        for (int d = 8; d >= 1; d >>= 1) s2 += __shfl_xor(s2, d, 16);
        float rs = rsqrtf(s2 * (1.0f / 96.0f) + 1e-5f);
#pragma unroll
        for (int c = 0; c < 6; ++c) {
            int col2 = q + 16 * c;
            float ov = v[c] * rs * g[col2] + be[col2];
            if (RELU) ov = fmaxf(ov, 0.0f);
            hout[((size_t)(col2 >> 5) * NN + rbase + rr) * 32 + (col2 & 31)] = f2bf_rne(ov);
        }
    }
}

// ---------------- final: MFMA [NN x 288] @ [288 x 64] + LN ----------------
__global__ __launch_bounds__(256)
void final_mfma_kernel(const u16* __restrict__ h0, const u16* __restrict__ h1,
                       const u16* __restrict__ h2, const u16* __restrict__ Wot,
                       const float* __restrict__ bo, const float* __restrict__ go,
                       const float* __restrict__ beo, float* __restrict__ out) {
    __shared__ float vb[16][68];
    int t = threadIdx.x;
    int w = t >> 6, l = t & 63;
    int col = w * 16 + (l & 15);
    int kb = (l >> 4) * 8;

    bf8_t bfrag[9];
#pragma unroll
    for (int s = 0; s < 9; ++s)
        bfrag[s] = *reinterpret_cast<const bf8_t*>(Wot + col * DJ + s * 32 + kb);

    int rbase = blockIdx.x * 16;
    size_t row = rbase + (l & 15);
    f4_t acc = {0.f, 0.f, 0.f, 0.f};
#pragma unroll
    for (int s = 0; s < 9; ++s) {
        const u16* hp = (s < 3) ? h0 : (s < 6) ? h1 : h2;
        bf8_t a = *reinterpret_cast<const bf8_t*>(hp + ((size_t)(s % 3) * NN + row) * 32 + kb);
        acc = __builtin_amdgcn_mfma_f32_16x16x32_bf16(a, bfrag[s], acc, 0, 0, 0);
    }
    float bcol = bo[col];
#pragma unroll
    for (int r = 0; r < 4; ++r)
        vb[(l >> 4) * 4 + r][col] = acc[r] + bcol;
    __syncthreads();

    int rr = t >> 4, q = t & 15;
    float4 v = *reinterpret_cast<const float4*>(&vb[rr][q * 4]);
    float s1 = (v.x + v.y) + (v.z + v.w);
#pragma unroll
    for (int d = 8; d >= 1; d >>= 1) s1 += __shfl_xor(s1, d, 16);
    float mu = s1 * (1.0f / 64.0f);
    float dx = v.x - mu, dy = v.y - mu, dz = v.z - mu, dw = v.w - mu;
    float s2 = (dx * dx + dy * dy) + (dz * dz + dw * dw);
#pragma unroll
    for (int d = 8; d >= 1; d >>= 1) s2 += __shfl_xor(s2, d, 16);
    float rs = rsqrtf(s2 * (1.0f / 64.0f) + 1e-5f);
    float4 gv = *reinterpret_cast<const float4*>(go + q * 4);
    float4 bv = *reinterpret_cast<const float4*>(beo + q * 4);
    float4 o;
    o.x = dx * rs * gv.x + bv.x;
    o.y = dy * rs * gv.y + bv.y;
    o.z = dz * rs * gv.z + bv.z;
    o.w = dw * rs * gv.w + bv.w;
    *reinterpret_cast<float4*>(out + (size_t)(rbase + rr) * DOUT + q * 4) = o;
}

// ---------------- launcher ----------------
extern "C" void kernel_launch(void* const* d_in, const int* in_sizes, int n_in,
                              void* d_out, int out_size, void* d_ws, size_t ws_size,
                              hipStream_t stream) {
    const float* x   = (const float*)d_in[0];
    const int*   src = (const int*)d_in[1];
    const int*   dst = (const int*)d_in[2];
    const float* ew  = (const float*)d_in[3];
    const float* W0  = (const float*)d_in[4];
    const float* b0  = (const float*)d_in[5];
    const float* g0  = (const float*)d_in[6];
    const float* be0 = (const float*)d_in[7];
    const float* W1  = (const float*)d_in[8];
    const float* b1  = (const float*)d_in[9];
    const float* g1  = (const float*)d_in[10];
    const float* be1 = (const float*)d_in[11];
    const float* W2  = (const float*)d_in[12];
    const float* b2  = (const float*)d_in[13];
    const float* g2  = (const float*)d_in[14];
    const float* be2 = (const float*)d_in[15];
    const float* Wo  = (const float*)d_in[16];
    const float* bo  = (const float*)d_in[17];
    const float* go  = (const float*)d_in[18];
    const float* beo = (const float*)d_in[19];
    float* out = (float*)d_out;

    char* wsb = (char*)d_ws;
    int*   deg_out  = (int*)(wsb + 0);            // [NN] -> out_norm f32 in place
    int*   cursor   = (int*)(wsb + 200000);       // [NN] -> stays int (deg_in)
    float* in_norm  = (float*)(wsb + 400000);     // [NN]
    u32*   slots    = (u32*)(wsb + 600064);       // [NN*DMAX] 12.8 MB
    u16*   xb       = (u16*)(wsb + 13400064);     // [3][NN][32] bf16
    u16*   h0       = (u16*)(wsb + 23000064);     // [3][NN][32]
    u16*   h1       = (u16*)(wsb + 32600064);
    u16*   h2       = (u16*)(wsb + 42200064);
    u16*   aggb     = (u16*)(wsb + 51800064);     // [3][NN][32] bf16
    u16*   Wbt      = (u16*)(wsb + 61400064);     // [3][96][96] bf16
    u16*   Wot      = (u16*)(wsb + 61455360);     // [64][288] bf16
    float* out_norm = (float*)deg_out;

    hipMemsetAsync(deg_out, 0, 400000, stream);   // deg_out + cursor
    pass1_kernel<<<NXCD * (NE / ECH), 256, 0, stream>>>(src, dst, ew, deg_out, cursor, slots);
    norm_kernel<<<(NN + 255) / 256, 256, 0, stream>>>(deg_out, cursor, in_norm);
    fixup_kernel<<<NN * (DMAX / 4) / 256, 256, 0, stream>>>(slots, cursor, out_norm);
    cast_kernel<<<(NN * 24 + 255) / 256, 256, 0, stream>>>(x, xb);
    castw_kernel<<<(3 * DD * DD + DOUT * DJ + 255) / 256, 256, 0, stream>>>(W0, W1, W2, Wo, Wbt, Wot);

    int agrid = (NN * 4 + 255) / 256;   // 782

    agg_kernel<<<agrid, 256, 0, stream>>>(xb, slots, cursor, in_norm, aggb);
    gemm_mfma_kernel<1><<<NN / 16, 384, 0, stream>>>(aggb, Wbt, b0, g0, be0, h0);

    agg_kernel<<<agrid, 256, 0, stream>>>(h0, slots, cursor, in_norm, aggb);
    gemm_mfma_kernel<1><<<NN / 16, 384, 0, stream>>>(aggb, Wbt + DD * DD, b1, g1, be1, h1);

    agg_kernel<<<agrid, 256, 0, stream>>>(h1, slots, cursor, in_norm, aggb);
    gemm_mfma_kernel<0><<<NN / 16, 384, 0, stream>>>(aggb, Wbt + 2 * DD * DD, b2, g2, be2, h2);

    final_mfma_kernel<<<NN / 16, 256, 0, stream>>>(h0, h1, h2, Wot, bo, go, beo, out);
}

// Round 10
// 210.584 us; speedup vs baseline: 1.1605x; 1.1605x over previous
//
#include <hip/hip_runtime.h>
#include <hip/hip_bf16.h>

#define NN 50000
#define NE 800000
#define DD 96
#define DOUT 64
#define DJ 288          // 3*DD
#define DMAX 64         // fixed CSR stride; max in-degree (Poisson(16)) << 64
#define NPX 6250        // nodes per XCD partition (8 * 6250 = NN)
#define NCH 32          // edge chunks
#define CHE (NE / NCH)  // 25000 edges per chunk

typedef unsigned short u16;
typedef unsigned int u32;
typedef short bf8_t __attribute__((ext_vector_type(8)));   // 8 bf16 in 4 VGPRs
typedef float f4_t __attribute__((ext_vector_type(4)));

// ---------------- bf16 helpers ----------------
__device__ __forceinline__ float bf_lo(u32 u) { return __uint_as_float(u << 16); }
__device__ __forceinline__ float bf_hi(u32 u) { return __uint_as_float(u & 0xffff0000u); }
__device__ __forceinline__ u16 f2bf_rne(float f) {
    u32 u = __float_as_uint(f);
    u32 r = (u + 0x7fffu + ((u >> 16) & 1u)) >> 16;
    return (u16)r;
}

// ---------------- phase A: per-(chunk, node-range) LDS histograms, NO global atomics ----------------
// 256 blocks: xcd = bid&7 -> node range [lo, lo+NPX); chunk = bid>>3 -> edge range.
__global__ __launch_bounds__(512)
void histA_kernel(const int* __restrict__ src, const int* __restrict__ dst,
                  u16* __restrict__ pin, u16* __restrict__ pout) {
    __shared__ int hin[NPX];
    __shared__ int hou[NPX];
    int xcd = blockIdx.x & 7, chunk = blockIdx.x >> 3;
    int lo = xcd * NPX;
    for (int j = threadIdx.x; j < NPX; j += 512) { hin[j] = 0; hou[j] = 0; }
    __syncthreads();
    int e0 = chunk * CHE;
    for (int e = e0 + threadIdx.x; e < e0 + CHE; e += 512) {
        int s = src[e], d = dst[e];
        int sl = s - lo, dl = d - lo;
        if ((unsigned)sl < NPX) atomicAdd(&hou[sl], 1);
        if ((unsigned)dl < NPX) atomicAdd(&hin[dl], 1);
    }
    __syncthreads();
    for (int j = threadIdx.x; j < NPX; j += 512) {
        pin[chunk * NN + lo + j] = (u16)hin[j];
        pout[chunk * NN + lo + j] = (u16)hou[j];
    }
}

// ---------------- scan: per-node chunk-scan -> bases, degrees, norms ----------------
__global__ __launch_bounds__(256)
void scan_kernel(const u16* __restrict__ pin, const u16* __restrict__ pout,
                 u16* __restrict__ pbase, int* __restrict__ deg_in,
                 float* __restrict__ out_norm, float* __restrict__ in_norm) {
    int i = blockIdx.x * 256 + threadIdx.x;
    if (i >= NN) return;
    int s = 0;
#pragma unroll
    for (int c = 0; c < NCH; ++c) {
        int t = pin[c * NN + i];
        pbase[c * NN + i] = (u16)s;
        s += t;
    }
    deg_in[i] = s;
    int so = 0;
#pragma unroll
    for (int c = 0; c < NCH; ++c) so += pout[c * NN + i];
    out_norm[i] = rsqrtf(fmaxf((float)so, 1.0f));
    in_norm[i]  = rsqrtf(fmaxf((float)s, 1.0f));
}

// ---------------- phase B: rank-place edges into slots; LDS atomics only ----------------
// Block (xcd, chunk) owns slot ranks [pbase[chunk][i], pbase[chunk][i]+count) for its
// range's nodes -> disjoint writes, deterministic set, zero device-scope atomics.
__global__ __launch_bounds__(512)
void place_kernel(const int* __restrict__ src, const int* __restrict__ dst,
                  const float* __restrict__ ew, const u16* __restrict__ pbase,
                  u32* __restrict__ slots) {
    __shared__ int cur[NPX];
    int xcd = blockIdx.x & 7, chunk = blockIdx.x >> 3;
    int lo = xcd * NPX;
    for (int j = threadIdx.x; j < NPX; j += 512)
        cur[j] = pbase[chunk * NN + lo + j];
    __syncthreads();
    int e0 = chunk * CHE;
    for (int e = e0 + threadIdx.x; e < e0 + CHE; e += 512) {
        int d = dst[e];
        int dl = d - lo;
        if ((unsigned)dl < NPX) {
            int s = src[e];
            float w = ew[e];
            int r = atomicAdd(&cur[dl], 1);
            if (r < DMAX)
                slots[d * DMAX + r] = (u32)s | ((u32)f2bf_rne(w) << 16);
        }
    }
}

// ---------------- cast x (f32) -> xb (bf16, contiguous [NN][96]) ----------------
__global__ void cast_kernel(const float* __restrict__ x, u16* __restrict__ xb) {
    int idx = blockIdx.x * 256 + threadIdx.x;
    if (idx < NN * DD / 4) {
        float4 v = *reinterpret_cast<const float4*>(x + (size_t)idx * 4);
        uint2 pk;
        pk.x = (u32)f2bf_rne(v.x) | ((u32)f2bf_rne(v.y) << 16);
        pk.y = (u32)f2bf_rne(v.z) | ((u32)f2bf_rne(v.w) << 16);
        *reinterpret_cast<uint2*>(xb + (size_t)idx * 4) = pk;
    }
}

// ---------------- cast+transpose weights: W0,W1,W2 -> Wbt[3][96][96]; Wo -> Wot[64][288] ----------------
__global__ void castw_kernel(const float* __restrict__ W0, const float* __restrict__ W1,
                             const float* __restrict__ W2, const float* __restrict__ Wo,
                             u16* __restrict__ Wbt, u16* __restrict__ Wot) {
    int idx = blockIdx.x * 256 + threadIdx.x;
    if (idx < 3 * DD * DD) {
        int L = idx / (DD * DD), rem = idx % (DD * DD);
        int c = rem / DD, k = rem % DD;
        const float* W = (L == 0) ? W0 : (L == 1) ? W1 : W2;
        Wbt[idx] = f2bf_rne(W[k * DD + c]);
    } else if (idx < 3 * DD * DD + DOUT * DJ) {
        int j = idx - 3 * DD * DD;
        int c = j / DJ, k = j % DJ;
        Wot[j] = f2bf_rne(Wo[k * DOUT + c]);
    }
}

// ---------------- slot-CSR aggregation (R7 structure: 12 threads/node, 4-deep) ----------------
__device__ __forceinline__ void accum8(float4& A, float4& B, const uint4& q, float w) {
    A.x = fmaf(bf_lo(q.x), w, A.x);
    A.y = fmaf(bf_hi(q.x), w, A.y);
    A.z = fmaf(bf_lo(q.y), w, A.z);
    A.w = fmaf(bf_hi(q.y), w, A.w);
    B.x = fmaf(bf_lo(q.z), w, B.x);
    B.y = fmaf(bf_hi(q.z), w, B.y);
    B.z = fmaf(bf_lo(q.w), w, B.z);
    B.w = fmaf(bf_hi(q.w), w, B.w);
}

__global__ __launch_bounds__(256)
void agg_kernel(const u16* __restrict__ h, const u32* __restrict__ slots,
                const int* __restrict__ deg_in, const float* __restrict__ out_norm,
                const float* __restrict__ in_norm, u16* __restrict__ aggb) {
    int tid = blockIdx.x * 256 + threadIdx.x;
    int i = tid / 12;
    if (i >= NN) return;
    int f0 = (tid % 12) * 8;
    int deg = min(deg_in[i], DMAX);
    int base = i * DMAX;

    float4 A0 = {0.f,0.f,0.f,0.f}, B0 = A0, A1 = A0, B1 = A0,
           A2 = A0, B2 = A0, A3 = A0, B3 = A0;
    int k = 0;
    for (; k + 4 <= deg; k += 4) {
        uint4 sl = *reinterpret_cast<const uint4*>(slots + base + k);  // broadcast x4
        int s0 = sl.x & 0xffffu, s1 = sl.y & 0xffffu, s2 = sl.z & 0xffffu, s3 = sl.w & 0xffffu;
        float c0 = bf_hi(sl.x) * out_norm[s0];
        float c1 = bf_hi(sl.y) * out_norm[s1];
        float c2 = bf_hi(sl.z) * out_norm[s2];
        float c3 = bf_hi(sl.w) * out_norm[s3];
        uint4 q0 = *reinterpret_cast<const uint4*>(h + (size_t)s0 * DD + f0);
        uint4 q1 = *reinterpret_cast<const uint4*>(h + (size_t)s1 * DD + f0);
        uint4 q2 = *reinterpret_cast<const uint4*>(h + (size_t)s2 * DD + f0);
        uint4 q3 = *reinterpret_cast<const uint4*>(h + (size_t)s3 * DD + f0);
        accum8(A0, B0, q0, c0);
        accum8(A1, B1, q1, c1);
        accum8(A2, B2, q2, c2);
        accum8(A3, B3, q3, c3);
    }
    for (; k < deg; ++k) {
        u32 sv = slots[base + k];
        int s = sv & 0xffffu;
        float c = bf_hi(sv) * out_norm[s];
        uint4 q = *reinterpret_cast<const uint4*>(h + (size_t)s * DD + f0);
        accum8(A0, B0, q, c);
    }
    float cn = in_norm[i];
    float r0 = ((A0.x + A1.x) + (A2.x + A3.x)) * cn;
    float r1 = ((A0.y + A1.y) + (A2.y + A3.y)) * cn;
    float r2 = ((A0.z + A1.z) + (A2.z + A3.z)) * cn;
    float r3 = ((A0.w + A1.w) + (A2.w + A3.w)) * cn;
    float r4 = ((B0.x + B1.x) + (B2.x + B3.x)) * cn;
    float r5 = ((B0.y + B1.y) + (B2.y + B3.y)) * cn;
    float r6 = ((B0.z + B1.z) + (B2.z + B3.z)) * cn;
    float r7 = ((B0.w + B1.w) + (B2.w + B3.w)) * cn;
    uint4 pk;
    pk.x = (u32)f2bf_rne(r0) | ((u32)f2bf_rne(r1) << 16);
    pk.y = (u32)f2bf_rne(r2) | ((u32)f2bf_rne(r3) << 16);
    pk.z = (u32)f2bf_rne(r4) | ((u32)f2bf_rne(r5) << 16);
    pk.w = (u32)f2bf_rne(r6) | ((u32)f2bf_rne(r7) << 16);
    *reinterpret_cast<uint4*>(aggb + (size_t)i * DD + f0) = pk;
}

// ---------------- MFMA GEMM [NN x 96] @ [96 x 96] + bias + LN (+ReLU) -> bf16 ----------------
// grid NN/16, block 384 = 6 waves; wave w -> output cols [16w, 16w+16). K = 96 = 3 MFMA steps.
template <int RELU>
__global__ __launch_bounds__(384)
void gemm_mfma_kernel(const u16* __restrict__ aggb, const u16* __restrict__ Wbt,
                      const float* __restrict__ b, const float* __restrict__ g,
                      const float* __restrict__ be, u16* __restrict__ hout) {
    __shared__ float vb[16][97];
    int t = threadIdx.x;
    int w = t >> 6, l = t & 63;
    int col = w * 16 + (l & 15);
    int kb = (l >> 4) * 8;

    bf8_t bfrag[3];
#pragma unroll
    for (int s = 0; s < 3; ++s)
        bfrag[s] = *reinterpret_cast<const bf8_t*>(Wbt + col * DD + s * 32 + kb);

    int rbase = blockIdx.x * 16;
    size_t row = rbase + (l & 15);
    f4_t acc = {0.f, 0.f, 0.f, 0.f};
#pragma unroll
    for (int s = 0; s < 3; ++s) {
        bf8_t a = *reinterpret_cast<const bf8_t*>(aggb + row * DD + s * 32 + kb);
        acc = __builtin_amdgcn_mfma_f32_16x16x32_bf16(a, bfrag[s], acc, 0, 0, 0);
    }
    float bcol = b[col];
#pragma unroll
    for (int r = 0; r < 4; ++r)
        vb[(l >> 4) * 4 + r][col] = acc[r] + bcol;
    __syncthreads();

    if (t < 256) {
        int rr = t >> 4, q = t & 15;
        float v[6];
#pragma unroll
        for (int c = 0; c < 6; ++c) v[c] = vb[rr][q + 16 * c];
        float s1 = ((v[0] + v[1]) + (v[2] + v[3])) + (v[4] + v[5]);
#pragma unroll
        for (int d = 8; d >= 1; d >>= 1) s1 += __shfl_xor(s1, d, 16);
        float mu = s1 * (1.0f / 96.0f);
        float s2 = 0.f;
#pragma unroll
        for (int c = 0; c < 6; ++c) { v[c] -= mu; s2 += v[c] * v[c]; }
#pragma unroll
        for (int d = 8; d >= 1; d >>= 1) s2 += __shfl_xor(s2, d, 16);
        float rs = rsqrtf(s2 * (1.0f / 96.0f) + 1e-5f);
#pragma unroll
        for (int c = 0; c < 6; ++c) {
            int col2 = q + 16 * c;
            float ov = v[c] * rs * g[col2] + be[col2];
            if (RELU) ov = fmaxf(ov, 0.0f);
            hout[(size_t)(rbase + rr) * DD + col2] = f2bf_rne(ov);
        }
    }
}

// ---------------- final: MFMA [NN x 288] @ [288 x 64] + LN ----------------
__global__ __launch_bounds__(256)
void final_mfma_kernel(const u16* __restrict__ h0, const u16* __restrict__ h1,
                       const u16* __restrict__ h2, const u16* __restrict__ Wot,
                       const float* __restrict__ bo, const float* __restrict__ go,
                       const float* __restrict__ beo, float* __restrict__ out) {
    __shared__ float vb[16][68];
    int t = threadIdx.x;
    int w = t >> 6, l = t & 63;
    int col = w * 16 + (l & 15);
    int kb = (l >> 4) * 8;

    bf8_t bfrag[9];
#pragma unroll
    for (int s = 0; s < 9; ++s)
        bfrag[s] = *reinterpret_cast<const bf8_t*>(Wot + col * DJ + s * 32 + kb);

    int rbase = blockIdx.x * 16;
    size_t row = rbase + (l & 15);
    f4_t acc = {0.f, 0.f, 0.f, 0.f};
#pragma unroll
    for (int s = 0; s < 9; ++s) {
        const u16* hp = (s < 3) ? h0 : (s < 6) ? h1 : h2;
        int ko = (s % 3) * 32 + kb;
        bf8_t a = *reinterpret_cast<const bf8_t*>(hp + row * DD + ko);
        acc = __builtin_amdgcn_mfma_f32_16x16x32_bf16(a, bfrag[s], acc, 0, 0, 0);
    }
    float bcol = bo[col];
#pragma unroll
    for (int r = 0; r < 4; ++r)
        vb[(l >> 4) * 4 + r][col] = acc[r] + bcol;
    __syncthreads();

    int rr = t >> 4, q = t & 15;
    float4 v = *reinterpret_cast<const float4*>(&vb[rr][q * 4]);
    float s1 = (v.x + v.y) + (v.z + v.w);
#pragma unroll
    for (int d = 8; d >= 1; d >>= 1) s1 += __shfl_xor(s1, d, 16);
    float mu = s1 * (1.0f / 64.0f);
    float dx = v.x - mu, dy = v.y - mu, dz = v.z - mu, dw = v.w - mu;
    float s2 = (dx * dx + dy * dy) + (dz * dz + dw * dw);
#pragma unroll
    for (int d = 8; d >= 1; d >>= 1) s2 += __shfl_xor(s2, d, 16);
    float rs = rsqrtf(s2 * (1.0f / 64.0f) + 1e-5f);
    float4 gv = *reinterpret_cast<const float4*>(go + q * 4);
    float4 bv = *reinterpret_cast<const float4*>(beo + q * 4);
    float4 o;
    o.x = dx * rs * gv.x + bv.x;
    o.y = dy * rs * gv.y + bv.y;
    o.z = dz * rs * gv.z + bv.z;
    o.w = dw * rs * gv.w + bv.w;
    *reinterpret_cast<float4*>(out + (size_t)(rbase + rr) * DOUT + q * 4) = o;
}

// ---------------- launcher ----------------
extern "C" void kernel_launch(void* const* d_in, const int* in_sizes, int n_in,
                              void* d_out, int out_size, void* d_ws, size_t ws_size,
                              hipStream_t stream) {
    const float* x   = (const float*)d_in[0];
    const int*   src = (const int*)d_in[1];
    const int*   dst = (const int*)d_in[2];
    const float* ew  = (const float*)d_in[3];
    const float* W0  = (const float*)d_in[4];
    const float* b0  = (const float*)d_in[5];
    const float* g0  = (const float*)d_in[6];
    const float* be0 = (const float*)d_in[7];
    const float* W1  = (const float*)d_in[8];
    const float* b1  = (const float*)d_in[9];
    const float* g1  = (const float*)d_in[10];
    const float* be1 = (const float*)d_in[11];
    const float* W2  = (const float*)d_in[12];
    const float* b2  = (const float*)d_in[13];
    const float* g2  = (const float*)d_in[14];
    const float* be2 = (const float*)d_in[15];
    const float* Wo  = (const float*)d_in[16];
    const float* bo  = (const float*)d_in[17];
    const float* go  = (const float*)d_in[18];
    const float* beo = (const float*)d_in[19];
    float* out = (float*)d_out;

    char* wsb = (char*)d_ws;
    u16*   pin      = (u16*)(wsb + 0);            // [NCH][NN] u16, 3.2 MB
    u16*   pout     = (u16*)(wsb + 3200000);      // [NCH][NN] u16
    u16*   pbase    = (u16*)(wsb + 6400000);      // [NCH][NN] u16
    float* out_norm = (float*)(wsb + 9600000);    // [NN]
    float* in_norm  = (float*)(wsb + 9800000);    // [NN]
    int*   deg_in   = (int*)(wsb + 10000000);     // [NN]
    u32*   slots    = (u32*)(wsb + 10200064);     // [NN*DMAX] 12.8 MB
    u16*   xb       = (u16*)(wsb + 23000064);     // [NN][96] bf16
    u16*   h0       = (u16*)(wsb + 32600064);
    u16*   h1       = (u16*)(wsb + 42200064);
    u16*   h2       = (u16*)(wsb + 51800064);
    u16*   aggb     = (u16*)(wsb + 61400064);     // [NN][96] bf16
    u16*   Wbt      = (u16*)(wsb + 71000064);     // [3][96][96] bf16
    u16*   Wot      = (u16*)(wsb + 71055360);     // [64][288] bf16 (ends ~71.1 MB)

    // CSR build: zero device-scope atomics, no memsets
    histA_kernel<<<8 * NCH, 512, 0, stream>>>(src, dst, pin, pout);
    scan_kernel<<<(NN + 255) / 256, 256, 0, stream>>>(pin, pout, pbase, deg_in,
                                                      out_norm, in_norm);
    place_kernel<<<8 * NCH, 512, 0, stream>>>(src, dst, ew, pbase, slots);
    cast_kernel<<<(NN * DD / 4 + 255) / 256, 256, 0, stream>>>(x, xb);
    castw_kernel<<<(3 * DD * DD + DOUT * DJ + 255) / 256, 256, 0, stream>>>(W0, W1, W2, Wo, Wbt, Wot);

    int agrid = (NN * 12 + 255) / 256;   // 2344

    agg_kernel<<<agrid, 256, 0, stream>>>(xb, slots, deg_in, out_norm, in_norm, aggb);
    gemm_mfma_kernel<1><<<NN / 16, 384, 0, stream>>>(aggb, Wbt, b0, g0, be0, h0);

    agg_kernel<<<agrid, 256, 0, stream>>>(h0, slots, deg_in, out_norm, in_norm, aggb);
    gemm_mfma_kernel<1><<<NN / 16, 384, 0, stream>>>(aggb, Wbt + DD * DD, b1, g1, be1, h1);

    agg_kernel<<<agrid, 256, 0, stream>>>(h1, slots, deg_in, out_norm, in_norm, aggb);
    gemm_mfma_kernel<0><<<NN / 16, 384, 0, stream>>>(aggb, Wbt + 2 * DD * DD, b2, g2, be2, h2);

    final_mfma_kernel<<<NN / 16, 256, 0, stream>>>(h0, h1, h2, Wot, bo, go, beo, out);
}

// Round 11
// 184.765 us; speedup vs baseline: 1.3226x; 1.1397x over previous
//
#include <hip/hip_runtime.h>
#include <hip/hip_bf16.h>

#define NN 50000
#define NE 800000
#define DD 96
#define DOUT 64
#define DJ 288          // 3*DD
#define DMAX 64         // fixed CSR stride; max in-degree (Poisson(16)) << 64
#define NCH 128         // edge chunks
#define CHE (NE / NCH)  // 6250 edges per chunk
#define NH (NN / 2)     // 25000 packed u32 counters (u16 pair per word)

typedef unsigned short u16;
typedef unsigned int u32;
typedef short bf8_t __attribute__((ext_vector_type(8)));   // 8 bf16 in 4 VGPRs
typedef float f4_t __attribute__((ext_vector_type(4)));

// ---------------- bf16 helpers ----------------
__device__ __forceinline__ float bf_lo(u32 u) { return __uint_as_float(u << 16); }
__device__ __forceinline__ float bf_hi(u32 u) { return __uint_as_float(u & 0xffff0000u); }
__device__ __forceinline__ u16 f2bf_rne(float f) {
    u32 u = __float_as_uint(f);
    u32 r = (u + 0x7fffu + ((u >> 16) & 1u)) >> 16;
    return (u16)r;
}

// ---------------- hist: full-range packed-u16 LDS histogram per chunk ----------------
// grid = 2*NCH: bid < NCH -> dst histogram (pin[chunk]); else src histogram (pout[chunk]).
// Whole 50000-node range in one 97.7 KB LDS array -> each edge stream read ONCE.
__global__ __launch_bounds__(1024)
void hist_kernel(const int* __restrict__ src, const int* __restrict__ dst,
                 u32* __restrict__ pin, u32* __restrict__ pout) {
    __shared__ u32 sh[NH];
    int bid = blockIdx.x;
    int isOut = bid >= NCH;
    int chunk = isOut ? bid - NCH : bid;
    const int* idx = isOut ? src : dst;
    for (int j = threadIdx.x; j < NH; j += 1024) sh[j] = 0;
    __syncthreads();
    int e0 = chunk * CHE;
    for (int e = e0 + threadIdx.x; e < e0 + CHE; e += 1024) {
        int d = idx[e];
        atomicAdd(&sh[d >> 1], 1u << ((d & 1) * 16));
    }
    __syncthreads();
    u32* outp = (isOut ? pout : pin) + chunk * NH;
    for (int j = threadIdx.x; j < NH; j += 1024) outp[j] = sh[j];
}

// ---------------- scan: per-node-pair chunk scan; pin -> pbase IN PLACE; norms ----------------
__global__ __launch_bounds__(256)
void scan_kernel(u32* __restrict__ pin /* becomes pbase in place */,
                 const u32* __restrict__ pout, int* __restrict__ deg_in,
                 float* __restrict__ out_norm, float* __restrict__ in_norm) {
    int j = blockIdx.x * 256 + threadIdx.x;   // packed-pair index: nodes 2j, 2j+1
    if (j >= NH) return;
    int s0 = 0, s1 = 0;
#pragma unroll 8
    for (int c = 0; c < NCH; ++c) {
        u32 v = pin[c * NH + j];
        pin[c * NH + j] = (u32)s0 | ((u32)s1 << 16);   // exclusive base for this chunk
        s0 += v & 0xffffu;
        s1 += v >> 16;
    }
    int i0 = 2 * j, i1 = 2 * j + 1;
    deg_in[i0] = s0;
    deg_in[i1] = s1;
    in_norm[i0] = rsqrtf(fmaxf((float)s0, 1.0f));
    in_norm[i1] = rsqrtf(fmaxf((float)s1, 1.0f));
    int o0 = 0, o1 = 0;
#pragma unroll 8
    for (int c = 0; c < NCH; ++c) {
        u32 v = pout[c * NH + j];
        o0 += v & 0xffffu;
        o1 += v >> 16;
    }
    out_norm[i0] = rsqrtf(fmaxf((float)o0, 1.0f));
    out_norm[i1] = rsqrtf(fmaxf((float)o1, 1.0f));
}

// ---------------- place: rank from packed LDS fetch-add; zero device atomics ----------------
// grid = NCH blocks; block loads its chunk's base slice into LDS, streams its 6250 edges.
__global__ __launch_bounds__(1024)
void place_kernel(const int* __restrict__ src, const int* __restrict__ dst,
                  const float* __restrict__ ew, const u32* __restrict__ pbase,
                  u32* __restrict__ slots) {
    __shared__ u32 cur[NH];
    int chunk = blockIdx.x;
    const u32* bp = pbase + chunk * NH;
    for (int j = threadIdx.x; j < NH; j += 1024) cur[j] = bp[j];
    __syncthreads();
    int e0 = chunk * CHE;
    for (int e = e0 + threadIdx.x; e < e0 + CHE; e += 1024) {
        int d = dst[e];
        int s = src[e];
        float w = ew[e];
        int sh = (d & 1) * 16;
        u32 old = atomicAdd(&cur[d >> 1], 1u << sh);
        int r = (old >> sh) & 0xffffu;
        if (r < DMAX)
            slots[d * DMAX + r] = (u32)s | ((u32)f2bf_rne(w) << 16);
    }
}

// ---------------- cast x (f32) -> xb (bf16, contiguous [NN][96]) ----------------
__global__ void cast_kernel(const float* __restrict__ x, u16* __restrict__ xb) {
    int idx = blockIdx.x * 256 + threadIdx.x;
    if (idx < NN * DD / 4) {
        float4 v = *reinterpret_cast<const float4*>(x + (size_t)idx * 4);
        uint2 pk;
        pk.x = (u32)f2bf_rne(v.x) | ((u32)f2bf_rne(v.y) << 16);
        pk.y = (u32)f2bf_rne(v.z) | ((u32)f2bf_rne(v.w) << 16);
        *reinterpret_cast<uint2*>(xb + (size_t)idx * 4) = pk;
    }
}

// ---------------- cast+transpose weights: W0,W1,W2 -> Wbt[3][96][96]; Wo -> Wot[64][288] ----------------
__global__ void castw_kernel(const float* __restrict__ W0, const float* __restrict__ W1,
                             const float* __restrict__ W2, const float* __restrict__ Wo,
                             u16* __restrict__ Wbt, u16* __restrict__ Wot) {
    int idx = blockIdx.x * 256 + threadIdx.x;
    if (idx < 3 * DD * DD) {
        int L = idx / (DD * DD), rem = idx % (DD * DD);
        int c = rem / DD, k = rem % DD;
        const float* W = (L == 0) ? W0 : (L == 1) ? W1 : W2;
        Wbt[idx] = f2bf_rne(W[k * DD + c]);
    } else if (idx < 3 * DD * DD + DOUT * DJ) {
        int j = idx - 3 * DD * DD;
        int c = j / DJ, k = j % DJ;
        Wot[j] = f2bf_rne(Wo[k * DOUT + c]);
    }
}

// ---------------- slot-CSR aggregation (R7 structure: 12 threads/node, 4-deep) ----------------
__device__ __forceinline__ void accum8(float4& A, float4& B, const uint4& q, float w) {
    A.x = fmaf(bf_lo(q.x), w, A.x);
    A.y = fmaf(bf_hi(q.x), w, A.y);
    A.z = fmaf(bf_lo(q.y), w, A.z);
    A.w = fmaf(bf_hi(q.y), w, A.w);
    B.x = fmaf(bf_lo(q.z), w, B.x);
    B.y = fmaf(bf_hi(q.z), w, B.y);
    B.z = fmaf(bf_lo(q.w), w, B.z);
    B.w = fmaf(bf_hi(q.w), w, B.w);
}

__global__ __launch_bounds__(256)
void agg_kernel(const u16* __restrict__ h, const u32* __restrict__ slots,
                const int* __restrict__ deg_in, const float* __restrict__ out_norm,
                const float* __restrict__ in_norm, u16* __restrict__ aggb) {
    int tid = blockIdx.x * 256 + threadIdx.x;
    int i = tid / 12;
    if (i >= NN) return;
    int f0 = (tid % 12) * 8;
    int deg = min(deg_in[i], DMAX);
    int base = i * DMAX;

    float4 A0 = {0.f,0.f,0.f,0.f}, B0 = A0, A1 = A0, B1 = A0,
           A2 = A0, B2 = A0, A3 = A0, B3 = A0;
    int k = 0;
    for (; k + 4 <= deg; k += 4) {
        uint4 sl = *reinterpret_cast<const uint4*>(slots + base + k);  // broadcast x4
        int s0 = sl.x & 0xffffu, s1 = sl.y & 0xffffu, s2 = sl.z & 0xffffu, s3 = sl.w & 0xffffu;
        float c0 = bf_hi(sl.x) * out_norm[s0];
        float c1 = bf_hi(sl.y) * out_norm[s1];
        float c2 = bf_hi(sl.z) * out_norm[s2];
        float c3 = bf_hi(sl.w) * out_norm[s3];
        uint4 q0 = *reinterpret_cast<const uint4*>(h + (size_t)s0 * DD + f0);
        uint4 q1 = *reinterpret_cast<const uint4*>(h + (size_t)s1 * DD + f0);
        uint4 q2 = *reinterpret_cast<const uint4*>(h + (size_t)s2 * DD + f0);
        uint4 q3 = *reinterpret_cast<const uint4*>(h + (size_t)s3 * DD + f0);
        accum8(A0, B0, q0, c0);
        accum8(A1, B1, q1, c1);
        accum8(A2, B2, q2, c2);
        accum8(A3, B3, q3, c3);
    }
    for (; k < deg; ++k) {
        u32 sv = slots[base + k];
        int s = sv & 0xffffu;
        float c = bf_hi(sv) * out_norm[s];
        uint4 q = *reinterpret_cast<const uint4*>(h + (size_t)s * DD + f0);
        accum8(A0, B0, q, c);
    }
    float cn = in_norm[i];
    float r0 = ((A0.x + A1.x) + (A2.x + A3.x)) * cn;
    float r1 = ((A0.y + A1.y) + (A2.y + A3.y)) * cn;
    float r2 = ((A0.z + A1.z) + (A2.z + A3.z)) * cn;
    float r3 = ((A0.w + A1.w) + (A2.w + A3.w)) * cn;
    float r4 = ((B0.x + B1.x) + (B2.x + B3.x)) * cn;
    float r5 = ((B0.y + B1.y) + (B2.y + B3.y)) * cn;
    float r6 = ((B0.z + B1.z) + (B2.z + B3.z)) * cn;
    float r7 = ((B0.w + B1.w) + (B2.w + B3.w)) * cn;
    uint4 pk;
    pk.x = (u32)f2bf_rne(r0) | ((u32)f2bf_rne(r1) << 16);
    pk.y = (u32)f2bf_rne(r2) | ((u32)f2bf_rne(r3) << 16);
    pk.z = (u32)f2bf_rne(r4) | ((u32)f2bf_rne(r5) << 16);
    pk.w = (u32)f2bf_rne(r6) | ((u32)f2bf_rne(r7) << 16);
    *reinterpret_cast<uint4*>(aggb + (size_t)i * DD + f0) = pk;
}

// ---------------- MFMA GEMM [NN x 96] @ [96 x 96] + bias + LN (+ReLU) -> bf16 ----------------
template <int RELU>
__global__ __launch_bounds__(384)
void gemm_mfma_kernel(const u16* __restrict__ aggb, const u16* __restrict__ Wbt,
                      const float* __restrict__ b, const float* __restrict__ g,
                      const float* __restrict__ be, u16* __restrict__ hout) {
    __shared__ float vb[16][97];
    int t = threadIdx.x;
    int w = t >> 6, l = t & 63;
    int col = w * 16 + (l & 15);
    int kb = (l >> 4) * 8;

    bf8_t bfrag[3];
#pragma unroll
    for (int s = 0; s < 3; ++s)
        bfrag[s] = *reinterpret_cast<const bf8_t*>(Wbt + col * DD + s * 32 + kb);

    int rbase = blockIdx.x * 16;
    size_t row = rbase + (l & 15);
    f4_t acc = {0.f, 0.f, 0.f, 0.f};
#pragma unroll
    for (int s = 0; s < 3; ++s) {
        bf8_t a = *reinterpret_cast<const bf8_t*>(aggb + row * DD + s * 32 + kb);
        acc = __builtin_amdgcn_mfma_f32_16x16x32_bf16(a, bfrag[s], acc, 0, 0, 0);
    }
    float bcol = b[col];
#pragma unroll
    for (int r = 0; r < 4; ++r)
        vb[(l >> 4) * 4 + r][col] = acc[r] + bcol;
    __syncthreads();

    if (t < 256) {
        int rr = t >> 4, q = t & 15;
        float v[6];
#pragma unroll
        for (int c = 0; c < 6; ++c) v[c] = vb[rr][q + 16 * c];
        float s1 = ((v[0] + v[1]) + (v[2] + v[3])) + (v[4] + v[5]);
#pragma unroll
        for (int d = 8; d >= 1; d >>= 1) s1 += __shfl_xor(s1, d, 16);
        float mu = s1 * (1.0f / 96.0f);
        float s2 = 0.f;
#pragma unroll
        for (int c = 0; c < 6; ++c) { v[c] -= mu; s2 += v[c] * v[c]; }
#pragma unroll
        for (int d = 8; d >= 1; d >>= 1) s2 += __shfl_xor(s2, d, 16);
        float rs = rsqrtf(s2 * (1.0f / 96.0f) + 1e-5f);
#pragma unroll
        for (int c = 0; c < 6; ++c) {
            int col2 = q + 16 * c;
            float ov = v[c] * rs * g[col2] + be[col2];
            if (RELU) ov = fmaxf(ov, 0.0f);
            hout[(size_t)(rbase + rr) * DD + col2] = f2bf_rne(ov);
        }
    }
}

// ---------------- final: MFMA [NN x 288] @ [288 x 64] + LN ----------------
__global__ __launch_bounds__(256)
void final_mfma_kernel(const u16* __restrict__ h0, const u16* __restrict__ h1,
                       const u16* __restrict__ h2, const u16* __restrict__ Wot,
                       const float* __restrict__ bo, const float* __restrict__ go,
                       const float* __restrict__ beo, float* __restrict__ out) {
    __shared__ float vb[16][68];
    int t = threadIdx.x;
    int w = t >> 6, l = t & 63;
    int col = w * 16 + (l & 15);
    int kb = (l >> 4) * 8;

    bf8_t bfrag[9];
#pragma unroll
    for (int s = 0; s < 9; ++s)
        bfrag[s] = *reinterpret_cast<const bf8_t*>(Wot + col * DJ + s * 32 + kb);

    int rbase = blockIdx.x * 16;
    size_t row = rbase + (l & 15);
    f4_t acc = {0.f, 0.f, 0.f, 0.f};
#pragma unroll
    for (int s = 0; s < 9; ++s) {
        const u16* hp = (s < 3) ? h0 : (s < 6) ? h1 : h2;
        int ko = (s % 3) * 32 + kb;
        bf8_t a = *reinterpret_cast<const bf8_t*>(hp + row * DD + ko);
        acc = __builtin_amdgcn_mfma_f32_16x16x32_bf16(a, bfrag[s], acc, 0, 0, 0);
    }
    float bcol = bo[col];
#pragma unroll
    for (int r = 0; r < 4; ++r)
        vb[(l >> 4) * 4 + r][col] = acc[r] + bcol;
    __syncthreads();

    int rr = t >> 4, q = t & 15;
    float4 v = *reinterpret_cast<const float4*>(&vb[rr][q * 4]);
    float s1 = (v.x + v.y) + (v.z + v.w);
#pragma unroll
    for (int d = 8; d >= 1; d >>= 1) s1 += __shfl_xor(s1, d, 16);
    float mu = s1 * (1.0f / 64.0f);
    float dx = v.x - mu, dy = v.y - mu, dz = v.z - mu, dw = v.w - mu;
    float s2 = (dx * dx + dy * dy) + (dz * dz + dw * dw);
#pragma unroll
    for (int d = 8; d >= 1; d >>= 1) s2 += __shfl_xor(s2, d, 16);
    float rs = rsqrtf(s2 * (1.0f / 64.0f) + 1e-5f);
    float4 gv = *reinterpret_cast<const float4*>(go + q * 4);
    float4 bv = *reinterpret_cast<const float4*>(beo + q * 4);
    float4 o;
    o.x = dx * rs * gv.x + bv.x;
    o.y = dy * rs * gv.y + bv.y;
    o.z = dz * rs * gv.z + bv.z;
    o.w = dw * rs * gv.w + bv.w;
    *reinterpret_cast<float4*>(out + (size_t)(rbase + rr) * DOUT + q * 4) = o;
}

// ---------------- launcher ----------------
extern "C" void kernel_launch(void* const* d_in, const int* in_sizes, int n_in,
                              void* d_out, int out_size, void* d_ws, size_t ws_size,
                              hipStream_t stream) {
    const float* x   = (const float*)d_in[0];
    const int*   src = (const int*)d_in[1];
    const int*   dst = (const int*)d_in[2];
    const float* ew  = (const float*)d_in[3];
    const float* W0  = (const float*)d_in[4];
    const float* b0  = (const float*)d_in[5];
    const float* g0  = (const float*)d_in[6];
    const float* be0 = (const float*)d_in[7];
    const float* W1  = (const float*)d_in[8];
    const float* b1  = (const float*)d_in[9];
    const float* g1  = (const float*)d_in[10];
    const float* be1 = (const float*)d_in[11];
    const float* W2  = (const float*)d_in[12];
    const float* b2  = (const float*)d_in[13];
    const float* g2  = (const float*)d_in[14];
    const float* be2 = (const float*)d_in[15];
    const float* Wo  = (const float*)d_in[16];
    const float* bo  = (const float*)d_in[17];
    const float* go  = (const float*)d_in[18];
    const float* beo = (const float*)d_in[19];
    float* out = (float*)d_out;

    char* wsb = (char*)d_ws;
    u32*   pin      = (u32*)(wsb + 0);            // [NCH][NH] u32 12.8 MB; becomes pbase
    u32*   pout     = (u32*)(wsb + 12800000);     // [NCH][NH] u32 12.8 MB
    float* out_norm = (float*)(wsb + 25600064);   // [NN]
    float* in_norm  = (float*)(wsb + 25800064);   // [NN]
    int*   deg_in   = (int*)(wsb + 26000064);     // [NN]
    u32*   slots    = (u32*)(wsb + 26200064);     // [NN*DMAX] 12.8 MB
    u16*   xb       = (u16*)(wsb + 39000064);     // [NN][96] bf16
    u16*   h0       = (u16*)(wsb + 48600064);
    u16*   h1       = (u16*)(wsb + 58200064);
    u16*   h2       = (u16*)(wsb + 67800064);
    u16*   aggb     = (u16*)(wsb + 77400064);     // [NN][96] bf16
    u16*   Wbt      = (u16*)(wsb + 87000064);     // [3][96][96] bf16
    u16*   Wot      = (u16*)(wsb + 87055360);     // [64][288] bf16 (ends ~87.1 MB)

    // CSR build: full-range packed LDS histograms, zero device atomics, no memsets
    hist_kernel<<<2 * NCH, 1024, 0, stream>>>(src, dst, pin, pout);
    scan_kernel<<<(NH + 255) / 256, 256, 0, stream>>>(pin, pout, deg_in, out_norm, in_norm);
    place_kernel<<<NCH, 1024, 0, stream>>>(src, dst, ew, pin /*=pbase*/, slots);
    cast_kernel<<<(NN * DD / 4 + 255) / 256, 256, 0, stream>>>(x, xb);
    castw_kernel<<<(3 * DD * DD + DOUT * DJ + 255) / 256, 256, 0, stream>>>(W0, W1, W2, Wo, Wbt, Wot);

    int agrid = (NN * 12 + 255) / 256;   // 2344

    agg_kernel<<<agrid, 256, 0, stream>>>(xb, slots, deg_in, out_norm, in_norm, aggb);
    gemm_mfma_kernel<1><<<NN / 16, 384, 0, stream>>>(aggb, Wbt, b0, g0, be0, h0);

    agg_kernel<<<agrid, 256, 0, stream>>>(h0, slots, deg_in, out_norm, in_norm, aggb);
    gemm_mfma_kernel<1><<<NN / 16, 384, 0, stream>>>(aggb, Wbt + DD * DD, b1, g1, be1, h1);

    agg_kernel<<<agrid, 256, 0, stream>>>(h1, slots, deg_in, out_norm, in_norm, aggb);
    gemm_mfma_kernel<0><<<NN / 16, 384, 0, stream>>>(aggb, Wbt + 2 * DD * DD, b2, g2, be2, h2);

    final_mfma_kernel<<<NN / 16, 256, 0, stream>>>(h0, h1, h2, Wot, bo, go, beo, out);
}

// Round 12
// 183.342 us; speedup vs baseline: 1.3329x; 1.0078x over previous
//
#include <hip/hip_runtime.h>
#include <hip/hip_bf16.h>

#define NN 50000
#define NE 800000
#define DD 96
#define DOUT 64
#define DJ 288          // 3*DD
#define DMAX 64         // fixed CSR stride; max in-degree (Poisson(16)) << 64
#define NCH 128         // edge chunks
#define CHE (NE / NCH)  // 6250 edges per chunk
#define NQ (NN / 4)     // 12500 packed u32 counters (u8 quad per word)

typedef unsigned short u16;
typedef unsigned int u32;
typedef short bf8_t __attribute__((ext_vector_type(8)));   // 8 bf16 in 4 VGPRs
typedef float f4_t __attribute__((ext_vector_type(4)));

// ---------------- bf16 helpers ----------------
__device__ __forceinline__ float bf_lo(u32 u) { return __uint_as_float(u << 16); }
__device__ __forceinline__ float bf_hi(u32 u) { return __uint_as_float(u & 0xffff0000u); }
__device__ __forceinline__ u16 f2bf_rne(float f) {
    u32 u = __float_as_uint(f);
    u32 r = (u + 0x7fffu + ((u >> 16) & 1u)) >> 16;
    return (u16)r;
}

// ---------------- hist: full-range u8-packed LDS histogram per chunk ----------------
// grid = 2*NCH: bid < NCH -> dst histogram (pin8[chunk]); else src histogram (pout8).
// 50 KB LDS (4 nodes per u32) -> 3 blocks/CU; per-chunk per-node count <= deg < 255.
__global__ __launch_bounds__(1024)
void hist_kernel(const int* __restrict__ src, const int* __restrict__ dst,
                 u32* __restrict__ pin8, u32* __restrict__ pout8) {
    __shared__ u32 sh[NQ];
    int bid = blockIdx.x;
    int isOut = bid >= NCH;
    int chunk = isOut ? bid - NCH : bid;
    const int* idx = isOut ? src : dst;
    for (int j = threadIdx.x; j < NQ; j += 1024) sh[j] = 0;
    __syncthreads();
    int e0 = chunk * CHE;
    for (int e = e0 + threadIdx.x; e < e0 + CHE; e += 1024) {
        int d = idx[e];
        atomicAdd(&sh[d >> 2], 1u << ((d & 3) * 8));
    }
    __syncthreads();
    u32* outp = (isOut ? pout8 : pin8) + chunk * NQ;
    for (int j = threadIdx.x; j < NQ; j += 1024) outp[j] = sh[j];
}

// ---------------- scan: per-node chunk scan; pin8 -> pbase8 IN PLACE; degrees + norms ----------------
__global__ __launch_bounds__(256)
void scan_kernel(u32* __restrict__ pin8 /* becomes pbase8 in place */,
                 const u32* __restrict__ pout8, int* __restrict__ deg_in,
                 float* __restrict__ out_norm, float* __restrict__ in_norm) {
    int j = blockIdx.x * 256 + threadIdx.x;   // packed-quad index: nodes 4j..4j+3
    if (j >= NQ) return;
    u32 s0 = 0, s1 = 0, s2 = 0, s3 = 0;
#pragma unroll 8
    for (int c = 0; c < NCH; ++c) {
        u32 v = pin8[c * NQ + j];
        pin8[c * NQ + j] = s0 | (s1 << 8) | (s2 << 16) | (s3 << 24);  // exclusive base
        s0 += v & 0xffu;
        s1 += (v >> 8) & 0xffu;
        s2 += (v >> 16) & 0xffu;
        s3 += (v >> 24) & 0xffu;
    }
    int i = 4 * j;
    deg_in[i] = s0; deg_in[i + 1] = s1; deg_in[i + 2] = s2; deg_in[i + 3] = s3;
    in_norm[i]     = rsqrtf(fmaxf((float)s0, 1.0f));
    in_norm[i + 1] = rsqrtf(fmaxf((float)s1, 1.0f));
    in_norm[i + 2] = rsqrtf(fmaxf((float)s2, 1.0f));
    in_norm[i + 3] = rsqrtf(fmaxf((float)s3, 1.0f));
    u32 o0 = 0, o1 = 0, o2 = 0, o3 = 0;
#pragma unroll 8
    for (int c = 0; c < NCH; ++c) {
        u32 v = pout8[c * NQ + j];
        o0 += v & 0xffu;
        o1 += (v >> 8) & 0xffu;
        o2 += (v >> 16) & 0xffu;
        o3 += (v >> 24) & 0xffu;
    }
    out_norm[i]     = rsqrtf(fmaxf((float)o0, 1.0f));
    out_norm[i + 1] = rsqrtf(fmaxf((float)o1, 1.0f));
    out_norm[i + 2] = rsqrtf(fmaxf((float)o2, 1.0f));
    out_norm[i + 3] = rsqrtf(fmaxf((float)o3, 1.0f));
}

// ---------------- place: rank from packed-u8 LDS fetch-add; zero device atomics ----------------
__global__ __launch_bounds__(1024)
void place_kernel(const int* __restrict__ src, const int* __restrict__ dst,
                  const float* __restrict__ ew, const u32* __restrict__ pbase8,
                  u32* __restrict__ slots) {
    __shared__ u32 cur[NQ];
    int chunk = blockIdx.x;
    const u32* bp = pbase8 + chunk * NQ;
    for (int j = threadIdx.x; j < NQ; j += 1024) cur[j] = bp[j];
    __syncthreads();
    int e0 = chunk * CHE;
    for (int e = e0 + threadIdx.x; e < e0 + CHE; e += 1024) {
        int d = dst[e];
        int s = src[e];
        float w = ew[e];
        int sh = (d & 3) * 8;
        u32 old = atomicAdd(&cur[d >> 2], 1u << sh);
        int r = (old >> sh) & 0xffu;
        if (r < DMAX)
            slots[d * DMAX + r] = (u32)s | ((u32)f2bf_rne(w) << 16);
    }
}

// ---------------- prep: cast x -> xb (bf16 [NN][96]); cast+transpose weights ----------------
__global__ void prep_kernel(const float* __restrict__ x, u16* __restrict__ xb,
                            const float* __restrict__ W0, const float* __restrict__ W1,
                            const float* __restrict__ W2, const float* __restrict__ Wo,
                            u16* __restrict__ Wbt, u16* __restrict__ Wot) {
    int idx = blockIdx.x * 256 + threadIdx.x;
    if (idx < NN * 24) {
        float4 v = *reinterpret_cast<const float4*>(x + (size_t)idx * 4);
        uint2 pk;
        pk.x = (u32)f2bf_rne(v.x) | ((u32)f2bf_rne(v.y) << 16);
        pk.y = (u32)f2bf_rne(v.z) | ((u32)f2bf_rne(v.w) << 16);
        *reinterpret_cast<uint2*>(xb + (size_t)idx * 4) = pk;
    } else {
        int j = idx - NN * 24;
        if (j < 3 * DD * DD) {
            int L = j / (DD * DD), rem = j % (DD * DD);
            int c = rem / DD, k = rem % DD;
            const float* W = (L == 0) ? W0 : (L == 1) ? W1 : W2;
            Wbt[j] = f2bf_rne(W[k * DD + c]);
        } else if (j < 3 * DD * DD + DOUT * DJ) {
            int jj = j - 3 * DD * DD;
            int c = jj / DJ, k = jj % DJ;
            Wot[jj] = f2bf_rne(Wo[k * DOUT + c]);
        }
    }
}

// ---------------- fused layer: agg (12 t/node -> LDS) + MFMA GEMM + LN (+ReLU) ----------------
// 384 threads, 32 nodes/block. Agg phase: node n = t/12, 8 features/thread, 4-deep MLP.
// MFMA phase: 6 waves x cols [16w,16w+16), two 16-row tiles each, A from LDS (stride 104
// u16 -> 2-way bank aliasing only). LN: two 16-row halves on t<256.
__device__ __forceinline__ void accum8(float4& A, float4& B, const uint4& q, float w) {
    A.x = fmaf(bf_lo(q.x), w, A.x);
    A.y = fmaf(bf_hi(q.x), w, A.y);
    A.z = fmaf(bf_lo(q.y), w, A.z);
    A.w = fmaf(bf_hi(q.y), w, A.w);
    B.x = fmaf(bf_lo(q.z), w, B.x);
    B.y = fmaf(bf_hi(q.z), w, B.y);
    B.z = fmaf(bf_lo(q.w), w, B.z);
    B.w = fmaf(bf_hi(q.w), w, B.w);
}

template <int RELU>
__global__ __launch_bounds__(384)
void layer_kernel(const u16* __restrict__ h, const u32* __restrict__ slots,
                  const int* __restrict__ deg_in, const float* __restrict__ out_norm,
                  const float* __restrict__ in_norm, const u16* __restrict__ Wbt,
                  const float* __restrict__ b, const float* __restrict__ g,
                  const float* __restrict__ be, u16* __restrict__ hout) {
    __shared__ u16 Al[32][104];     // bf16 agg rows, padded stride
    __shared__ float vb[32][97];
    int t = threadIdx.x;
    int w = t >> 6, l = t & 63;
    int col = w * 16 + (l & 15);
    int kb = (l >> 4) * 8;

    bf8_t bfrag[3];
#pragma unroll
    for (int s = 0; s < 3; ++s)
        bfrag[s] = *reinterpret_cast<const bf8_t*>(Wbt + col * DD + s * 32 + kb);

    int rbase = blockIdx.x * 32;

    // ---- aggregation into LDS
    {
        int n = t / 12;                 // 384 = 32 * 12 exactly
        int f0 = (t % 12) * 8;
        int i = rbase + n;
        float4 A0 = {0.f,0.f,0.f,0.f}, B0 = A0, A1 = A0, B1 = A0,
               A2 = A0, B2 = A0, A3 = A0, B3 = A0;
        float cn = 0.0f;
        if (i < NN) {
            int deg = min(deg_in[i], DMAX);
            int base = i * DMAX;
            cn = in_norm[i];
            int k = 0;
            for (; k + 4 <= deg; k += 4) {
                uint4 sl = *reinterpret_cast<const uint4*>(slots + base + k);
                int s0 = sl.x & 0xffffu, s1 = sl.y & 0xffffu, s2 = sl.z & 0xffffu, s3 = sl.w & 0xffffu;
                float c0 = bf_hi(sl.x) * out_norm[s0];
                float c1 = bf_hi(sl.y) * out_norm[s1];
                float c2 = bf_hi(sl.z) * out_norm[s2];
                float c3 = bf_hi(sl.w) * out_norm[s3];
                uint4 q0 = *reinterpret_cast<const uint4*>(h + (size_t)s0 * DD + f0);
                uint4 q1 = *reinterpret_cast<const uint4*>(h + (size_t)s1 * DD + f0);
                uint4 q2 = *reinterpret_cast<const uint4*>(h + (size_t)s2 * DD + f0);
                uint4 q3 = *reinterpret_cast<const uint4*>(h + (size_t)s3 * DD + f0);
                accum8(A0, B0, q0, c0);
                accum8(A1, B1, q1, c1);
                accum8(A2, B2, q2, c2);
                accum8(A3, B3, q3, c3);
            }
            for (; k < deg; ++k) {
                u32 sv = slots[base + k];
                int s = sv & 0xffffu;
                float c = bf_hi(sv) * out_norm[s];
                uint4 q = *reinterpret_cast<const uint4*>(h + (size_t)s * DD + f0);
                accum8(A0, B0, q, c);
            }
        }
        float r0 = ((A0.x + A1.x) + (A2.x + A3.x)) * cn;
        float r1 = ((A0.y + A1.y) + (A2.y + A3.y)) * cn;
        float r2 = ((A0.z + A1.z) + (A2.z + A3.z)) * cn;
        float r3 = ((A0.w + A1.w) + (A2.w + A3.w)) * cn;
        float r4 = ((B0.x + B1.x) + (B2.x + B3.x)) * cn;
        float r5 = ((B0.y + B1.y) + (B2.y + B3.y)) * cn;
        float r6 = ((B0.z + B1.z) + (B2.z + B3.z)) * cn;
        float r7 = ((B0.w + B1.w) + (B2.w + B3.w)) * cn;
        uint4 pk;
        pk.x = (u32)f2bf_rne(r0) | ((u32)f2bf_rne(r1) << 16);
        pk.y = (u32)f2bf_rne(r2) | ((u32)f2bf_rne(r3) << 16);
        pk.z = (u32)f2bf_rne(r4) | ((u32)f2bf_rne(r5) << 16);
        pk.w = (u32)f2bf_rne(r6) | ((u32)f2bf_rne(r7) << 16);
        *reinterpret_cast<uint4*>(&Al[n][f0]) = pk;
    }
    __syncthreads();

    // ---- MFMA: cols [16w,16w+16), row tiles 0-15 and 16-31
    f4_t acc0 = {0.f, 0.f, 0.f, 0.f}, acc1 = {0.f, 0.f, 0.f, 0.f};
#pragma unroll
    for (int s = 0; s < 3; ++s) {
        bf8_t a0 = *reinterpret_cast<const bf8_t*>(&Al[l & 15][s * 32 + kb]);
        bf8_t a1 = *reinterpret_cast<const bf8_t*>(&Al[16 + (l & 15)][s * 32 + kb]);
        acc0 = __builtin_amdgcn_mfma_f32_16x16x32_bf16(a0, bfrag[s], acc0, 0, 0, 0);
        acc1 = __builtin_amdgcn_mfma_f32_16x16x32_bf16(a1, bfrag[s], acc1, 0, 0, 0);
    }
    float bcol = b[col];
#pragma unroll
    for (int r = 0; r < 4; ++r) {
        vb[(l >> 4) * 4 + r][col] = acc0[r] + bcol;
        vb[16 + (l >> 4) * 4 + r][col] = acc1[r] + bcol;
    }
    __syncthreads();

    // ---- LN over 96 cols, 16 lanes/row, two 16-row halves
#pragma unroll
    for (int half = 0; half < 2; ++half) {
        if (t < 256) {
            int rr = half * 16 + (t >> 4), q = t & 15;
            float v[6];
#pragma unroll
            for (int c = 0; c < 6; ++c) v[c] = vb[rr][q + 16 * c];
            float s1 = ((v[0] + v[1]) + (v[2] + v[3])) + (v[4] + v[5]);
#pragma unroll
            for (int d = 8; d >= 1; d >>= 1) s1 += __shfl_xor(s1, d, 16);
            float mu = s1 * (1.0f / 96.0f);
            float s2 = 0.f;
#pragma unroll
            for (int c = 0; c < 6; ++c) { v[c] -= mu; s2 += v[c] * v[c]; }
#pragma unroll
            for (int d = 8; d >= 1; d >>= 1) s2 += __shfl_xor(s2, d, 16);
            float rs = rsqrtf(s2 * (1.0f / 96.0f) + 1e-5f);
            int row = rbase + rr;
            if (row < NN) {
#pragma unroll
                for (int c = 0; c < 6; ++c) {
                    int col2 = q + 16 * c;
                    float ov = v[c] * rs * g[col2] + be[col2];
                    if (RELU) ov = fmaxf(ov, 0.0f);
                    hout[(size_t)row * DD + col2] = f2bf_rne(ov);
                }
            }
        }
    }
}

// ---------------- final: MFMA [NN x 288] @ [288 x 64] + LN ----------------
__global__ __launch_bounds__(256)
void final_mfma_kernel(const u16* __restrict__ h0, const u16* __restrict__ h1,
                       const u16* __restrict__ h2, const u16* __restrict__ Wot,
                       const float* __restrict__ bo, const float* __restrict__ go,
                       const float* __restrict__ beo, float* __restrict__ out) {
    __shared__ float vb[16][68];
    int t = threadIdx.x;
    int w = t >> 6, l = t & 63;
    int col = w * 16 + (l & 15);
    int kb = (l >> 4) * 8;

    bf8_t bfrag[9];
#pragma unroll
    for (int s = 0; s < 9; ++s)
        bfrag[s] = *reinterpret_cast<const bf8_t*>(Wot + col * DJ + s * 32 + kb);

    int rbase = blockIdx.x * 16;
    size_t row = rbase + (l & 15);
    f4_t acc = {0.f, 0.f, 0.f, 0.f};
#pragma unroll
    for (int s = 0; s < 9; ++s) {
        const u16* hp = (s < 3) ? h0 : (s < 6) ? h1 : h2;
        int ko = (s % 3) * 32 + kb;
        bf8_t a = *reinterpret_cast<const bf8_t*>(hp + row * DD + ko);
        acc = __builtin_amdgcn_mfma_f32_16x16x32_bf16(a, bfrag[s], acc, 0, 0, 0);
    }
    float bcol = bo[col];
#pragma unroll
    for (int r = 0; r < 4; ++r)
        vb[(l >> 4) * 4 + r][col] = acc[r] + bcol;
    __syncthreads();

    int rr = t >> 4, q = t & 15;
    float4 v = *reinterpret_cast<const float4*>(&vb[rr][q * 4]);
    float s1 = (v.x + v.y) + (v.z + v.w);
#pragma unroll
    for (int d = 8; d >= 1; d >>= 1) s1 += __shfl_xor(s1, d, 16);
    float mu = s1 * (1.0f / 64.0f);
    float dx = v.x - mu, dy = v.y - mu, dz = v.z - mu, dw = v.w - mu;
    float s2 = (dx * dx + dy * dy) + (dz * dz + dw * dw);
#pragma unroll
    for (int d = 8; d >= 1; d >>= 1) s2 += __shfl_xor(s2, d, 16);
    float rs = rsqrtf(s2 * (1.0f / 64.0f) + 1e-5f);
    float4 gv = *reinterpret_cast<const float4*>(go + q * 4);
    float4 bv = *reinterpret_cast<const float4*>(beo + q * 4);
    float4 o;
    o.x = dx * rs * gv.x + bv.x;
    o.y = dy * rs * gv.y + bv.y;
    o.z = dz * rs * gv.z + bv.z;
    o.w = dw * rs * gv.w + bv.w;
    *reinterpret_cast<float4*>(out + (size_t)(rbase + rr) * DOUT + q * 4) = o;
}

// ---------------- launcher ----------------
extern "C" void kernel_launch(void* const* d_in, const int* in_sizes, int n_in,
                              void* d_out, int out_size, void* d_ws, size_t ws_size,
                              hipStream_t stream) {
    const float* x   = (const float*)d_in[0];
    const int*   src = (const int*)d_in[1];
    const int*   dst = (const int*)d_in[2];
    const float* ew  = (const float*)d_in[3];
    const float* W0  = (const float*)d_in[4];
    const float* b0  = (const float*)d_in[5];
    const float* g0  = (const float*)d_in[6];
    const float* be0 = (const float*)d_in[7];
    const float* W1  = (const float*)d_in[8];
    const float* b1  = (const float*)d_in[9];
    const float* g1  = (const float*)d_in[10];
    const float* be1 = (const float*)d_in[11];
    const float* W2  = (const float*)d_in[12];
    const float* b2  = (const float*)d_in[13];
    const float* g2  = (const float*)d_in[14];
    const float* be2 = (const float*)d_in[15];
    const float* Wo  = (const float*)d_in[16];
    const float* bo  = (const float*)d_in[17];
    const float* go  = (const float*)d_in[18];
    const float* beo = (const float*)d_in[19];
    float* out = (float*)d_out;

    char* wsb = (char*)d_ws;
    u32*   pin8     = (u32*)(wsb + 0);            // [NCH][NQ] u32 6.4 MB; becomes pbase8
    u32*   pout8    = (u32*)(wsb + 6400000);      // [NCH][NQ] u32 6.4 MB
    float* out_norm = (float*)(wsb + 12800000);   // [NN]
    float* in_norm  = (float*)(wsb + 13000000);   // [NN]
    int*   deg_in   = (int*)(wsb + 13200000);     // [NN]
    u32*   slots    = (u32*)(wsb + 13400064);     // [NN*DMAX] 12.8 MB
    u16*   xb       = (u16*)(wsb + 26200064);     // [NN][96] bf16
    u16*   h0       = (u16*)(wsb + 35800064);
    u16*   h1       = (u16*)(wsb + 45400064);
    u16*   h2       = (u16*)(wsb + 55000064);
    u16*   Wbt      = (u16*)(wsb + 64600064);     // [3][96][96] bf16
    u16*   Wot      = (u16*)(wsb + 64655360);     // [64][288] bf16 (ends ~64.7 MB)

    // CSR build: u8-packed full-range LDS histograms, zero device atomics, no memsets
    hist_kernel<<<2 * NCH, 1024, 0, stream>>>(src, dst, pin8, pout8);
    scan_kernel<<<(NQ + 255) / 256, 256, 0, stream>>>(pin8, pout8, deg_in, out_norm, in_norm);
    place_kernel<<<NCH, 1024, 0, stream>>>(src, dst, ew, pin8 /*=pbase8*/, slots);
    prep_kernel<<<(NN * 24 + 3 * DD * DD + DOUT * DJ + 255) / 256, 256, 0, stream>>>(
        x, xb, W0, W1, W2, Wo, Wbt, Wot);

    int lgrid = (NN + 31) / 32;   // 1563

    layer_kernel<1><<<lgrid, 384, 0, stream>>>(xb, slots, deg_in, out_norm, in_norm,
                                               Wbt, b0, g0, be0, h0);
    layer_kernel<1><<<lgrid, 384, 0, stream>>>(h0, slots, deg_in, out_norm, in_norm,
                                               Wbt + DD * DD, b1, g1, be1, h1);
    layer_kernel<0><<<lgrid, 384, 0, stream>>>(h1, slots, deg_in, out_norm, in_norm,
                                               Wbt + 2 * DD * DD, b2, g2, be2, h2);

    final_mfma_kernel<<<NN / 16, 256, 0, stream>>>(h0, h1, h2, Wot, bo, go, beo, out);
}